// Round 7
// baseline (307.486 us; speedup 1.0000x reference)
//
#include <hip/hip_runtime.h>
#include <math.h>

#define NB 4096
#define NN 64

typedef _Float16 h8 __attribute__((ext_vector_type(8)));
typedef float f4 __attribute__((ext_vector_type(4)));
typedef unsigned long long u64;

typedef const __attribute__((address_space(1))) void* gas_t;
typedef __attribute__((address_space(3))) void* las_t;

__device__ __forceinline__ void gload16(const void* g, void* l) {
  __builtin_amdgcn_global_load_lds((gas_t)g, (las_t)l, 16, 0, 0);
}

// raw barrier: no vmcnt/lgkmcnt drain (T3/T4 — loads stay in flight)
__device__ __forceinline__ void rbar() {
  asm volatile("" ::: "memory");
  __builtin_amdgcn_s_barrier();
  asm volatile("" ::: "memory");
}

// counted wait on own outstanding VMEM ops; MUST precede rbar() when the
// waited-on data is consumed by other waves (vmcnt is per-wave!)
template<int N> __device__ __forceinline__ void waitv() {
  if constexpr (N == 0)      asm volatile("s_waitcnt vmcnt(0)" ::: "memory");
  else                       asm volatile("s_waitcnt vmcnt(1)" ::: "memory");
  __builtin_amdgcn_sched_barrier(0);
}

// swizzled activation addressing: 64 rows x 128 f16 cols, 256 B row stride,
// byte ^= (row&7)<<4  (bank-conflict-free column access, G4). Bijective per row.
__device__ __forceinline__ int aoff(int row, int colb) {
  return row * 256 + (colb ^ ((row & 7) << 4));
}
__device__ __forceinline__ h8 ald8(const char* a, int row, int colb) {
  return *(const h8*)(a + aoff(row, colb));
}
__device__ __forceinline__ void ast8(char* a, int row, int colb, h8 v) {
  *(h8*)(a + aoff(row, colb)) = v;
}
__device__ __forceinline__ _Float16 ald(const char* a, int row, int colb) {
  return *(const _Float16*)(a + aoff(row, colb));
}
__device__ __forceinline__ void ast(char* a, int row, int colb, _Float16 v) {
  *(_Float16*)(a + aoff(row, colb)) = v;
}

// ---------------- weight prep: fp32 -> f16 (+ K/O zero padding) ----------------
//  [0      ,  4096) Wl1p [128][32]  (K 20->32 pad)
//  [4096   ,  8192) Wl2p [32][128]  (O 20->32 pad)
//  [8192   , 12288) W11p [128][32]  (K 27->32 pad)
//  [12288  , 28672) W12  [128][128]
//  [28672  , 45056) W21
//  [45056  , 61440) W22
//  [61440  , 94208) Wv   2x[128][128]
//  [94208  ,126976) Wo   2x[128][128]
//  [126976 ,159744) Wf1
//  [159744 ,192512) Wf2
__global__ void prep_kernel(
    const float* __restrict__ W_l1, const float* __restrict__ W_l2,
    const float* __restrict__ W11, const float* __restrict__ W12,
    const float* __restrict__ W21, const float* __restrict__ W22,
    const float* __restrict__ Wqkv, const float* __restrict__ Wo,
    const float* __restrict__ Wf1, const float* __restrict__ Wf2,
    _Float16* __restrict__ ws)
{
  const int e = blockIdx.x * 256 + threadIdx.x;
  float v;
  if (e < 4096) { const int o = e >> 5, k = e & 31; v = (k < 20) ? W_l1[o * 20 + k] : 0.f; }
  else if (e < 8192) { const int i = e - 4096; const int o = i >> 7, k = i & 127; v = (o < 20) ? W_l2[o * 128 + k] : 0.f; }
  else if (e < 12288) { const int i = e - 8192; const int o = i >> 5, k = i & 31; v = (k < 27) ? W11[o * 27 + k] : 0.f; }
  else if (e < 28672) v = W12[e - 12288];
  else if (e < 45056) v = W21[e - 28672];
  else if (e < 61440) v = W22[e - 45056];
  else if (e < 94208) { const int i = e - 61440; const int l = i >> 14, j = i & 16383; v = Wqkv[l * 49152 + 32768 + j]; }
  else if (e < 126976) v = Wo[e - 94208];
  else if (e < 159744) v = Wf1[e - 126976];
  else v = Wf2[e - 159744];
  ws[e] = (_Float16)v;
}

// ---------------- chunk staging: 4 KB = 256 x 16B units, 1 unit/thread ----------------
__device__ __forceinline__ void stage64(const _Float16* __restrict__ Wp, int KT,
                                        int kc, int oc, char* buf, int tid) {
  const int o = tid >> 2, kq = tid & 3;
  const int kreal = kq ^ ((o >> 1) & 3);
  gload16(Wp + (oc * 64 + o) * KT + kc * 32 + kreal * 8, buf + tid * 16);
}
// O=32 weight (lidar2, KT=128), chunk = 32 rows x 64 k; unit (o,u) holds u^(o&7)
__device__ __forceinline__ void stage32(const _Float16* __restrict__ Wp,
                                        int kc, char* buf, int tid) {
  const int o = tid >> 3, u = tid & 7;
  const int ureal = u ^ (o & 7);
  gload16(Wp + o * 128 + kc * 64 + ureal * 8, buf + tid * 16);
}

// ---------------- streamed matmul stage (O=128), both graphs ----------------
// Invariant entering each iteration q: chunks q and q+1 in flight (issued),
// chunk q-1 fully consumed. Per iteration: waitv(1) [own chunk-q landed] ->
// rbar [ALL waves' chunk-q landed; all reads of chunk q-1 done] -> issue
// chunk q+2 (or pf for the next stage) -> read chunk q -> MFMA.
template<int KT, bool RELU, bool RESID, bool CONT, typename PF>
__device__ __forceinline__ void mm2_s64(
    const _Float16* __restrict__ Wp, const float* __restrict__ bias,
    const char* s0, const char* s1, int scb,
    char* d0, char* d1,
    const char* r0, const char* r1,
    char* wbase, int& wbi, int tid, PF&& pf)
{
  constexpr int NK = KT / 32, NCH = 2 * NK;
  const int lane = tid & 63, wv = tid >> 6, lc = lane & 15, kg = lane >> 4;
  const int row0 = wv * 16 + lc;

  h8 af0[NK], af1[NK];
#pragma unroll
  for (int i = 0; i < NK; ++i) {
    af0[i] = ald8(s0, row0, scb + i * 64 + kg * 16);
    af1[i] = ald8(s1, row0, scb + i * 64 + kg * 16);
  }
  f4 acc0[8], acc1[8];
#pragma unroll
  for (int t = 0; t < 8; ++t) { acc0[t] = (f4){0.f,0.f,0.f,0.f}; acc1[t] = (f4){0.f,0.f,0.f,0.f}; }

#pragma unroll
  for (int q = 0; q < NCH; ++q) {
    if (!CONT && q == NCH - 1) waitv<0>(); else waitv<1>();   // own chunk-q landed
    rbar();                                                    // everyone's chunk-q landed
    if (q + 2 < NCH) stage64(Wp, KT, (q + 2) >> 1, (q + 2) & 1,
                             wbase + ((wbi + q + 2) % 3) * 4096, tid);
    else if constexpr (CONT) pf(q + 2 - NCH, (wbi + q + 2) % 3);

    const char* wb = wbase + ((wbi + q) % 3) * 4096;
    const int kc = q >> 1, oc = q & 1;
    h8 bf[4];
#pragma unroll
    for (int t = 0; t < 4; ++t) {
      const int o = t * 16 + lc;
      const int kq = kg ^ ((o >> 1) & 3);
      bf[t] = *(const h8*)(wb + (o * 4 + kq) * 16);
    }
#pragma unroll
    for (int t = 0; t < 4; ++t)
      acc0[oc * 4 + t] = __builtin_amdgcn_mfma_f32_16x16x32_f16(af0[kc], bf[t], acc0[oc * 4 + t], 0, 0, 0);
#pragma unroll
    for (int t = 0; t < 4; ++t)
      acc1[oc * 4 + t] = __builtin_amdgcn_mfma_f32_16x16x32_f16(af1[kc], bf[t], acc1[oc * 4 + t], 0, 0, 0);
  }
  wbi = (wbi + NCH) % 3;

  const int rbase = wv * 16 + kg * 4;
#pragma unroll
  for (int t = 0; t < 8; ++t) {
    const int col = t * 16 + lc;
    const float bv = bias[col];
#pragma unroll
    for (int r = 0; r < 4; ++r) {
      float v0 = acc0[t][r] + bv, v1 = acc1[t][r] + bv;
      if constexpr (RESID) {
        v0 += (float)ald(r0, rbase + r, col * 2);
        v1 += (float)ald(r1, rbase + r, col * 2);
      }
      if constexpr (RELU) { v0 = fmaxf(v0, 0.f); v1 = fmaxf(v1, 0.f); }
      ast(d0, rbase + r, col * 2, (_Float16)v0);
      ast(d1, rbase + r, col * 2, (_Float16)v1);
    }
  }
}

// lidar2 stage: KT=128, O=32(->20 cols), dst = XC cols 7..26 (byte base 78)
template<typename PF>
__device__ __forceinline__ void mm2_s32(
    const _Float16* __restrict__ Wp, const float* __restrict__ bias,
    const char* s0, const char* s1,
    char* d0, char* d1,
    char* wbase, int& wbi, int tid, PF&& pf)
{
  const int lane = tid & 63, wv = tid >> 6, lc = lane & 15, kg = lane >> 4;
  const int row0 = wv * 16 + lc;
  h8 af0[4], af1[4];
#pragma unroll
  for (int i = 0; i < 4; ++i) {
    af0[i] = ald8(s0, row0, i * 64 + kg * 16);
    af1[i] = ald8(s1, row0, i * 64 + kg * 16);
  }
  f4 a0[2], a1[2];
  a0[0] = a0[1] = a1[0] = a1[1] = (f4){0.f,0.f,0.f,0.f};
#pragma unroll
  for (int q = 0; q < 2; ++q) {
    waitv<1>();
    rbar();
    pf(q, (wbi + q + 2) % 3);       // always CONT (next: W11)
    const char* wb = wbase + ((wbi + q) % 3) * 4096;
#pragma unroll
    for (int ks = 0; ks < 2; ++ks) {
      h8 bf[2];
#pragma unroll
      for (int t = 0; t < 2; ++t) {
        const int o = t * 16 + lc;
        const int u = (ks * 4 + kg) ^ (o & 7);
        bf[t] = *(const h8*)(wb + (o * 8 + u) * 16);
      }
#pragma unroll
      for (int t = 0; t < 2; ++t) {
        a0[t] = __builtin_amdgcn_mfma_f32_16x16x32_f16(af0[q * 2 + ks], bf[t], a0[t], 0, 0, 0);
        a1[t] = __builtin_amdgcn_mfma_f32_16x16x32_f16(af1[q * 2 + ks], bf[t], a1[t], 0, 0, 0);
      }
    }
  }
  wbi = (wbi + 2) % 3;
  const int rbase = wv * 16 + kg * 4;
#pragma unroll
  for (int t = 0; t < 2; ++t) {
    const int col = t * 16 + lc;
    if (col < 20) {
      const float bv = bias[col];
#pragma unroll
      for (int r = 0; r < 4; ++r) {
        float v0 = fmaxf(a0[t][r] + bv, 0.f), v1 = fmaxf(a1[t][r] + bv, 0.f);
        ast(d0, rbase + r, 78 + col * 2, (_Float16)v0);
        ast(d1, rbase + r, 78 + col * 2, (_Float16)v1);
      }
    }
  }
}

// MFMA aggregation, 128 wide: dst[j][f] = sum_i M'[i][j] src[i][f]
__device__ __forceinline__ void agg128(const u64* mcol, const char* src, char* dst, int tid)
{
  const int lane = tid & 63, wv = tid >> 6, lc = lane & 15, kg = lane >> 4;
  const int c0 = wv * 32 + lc;
  u64 mrow[4];
#pragma unroll
  for (int rt = 0; rt < 4; ++rt) mrow[rt] = mcol[rt * 16 + lc];
  f4 acc[4][2];
#pragma unroll
  for (int rt = 0; rt < 4; ++rt) { acc[rt][0] = (f4){0.f,0.f,0.f,0.f}; acc[rt][1] = (f4){0.f,0.f,0.f,0.f}; }
#pragma unroll
  for (int ks = 0; ks < 2; ++ks) {
    h8 bf[2];
#pragma unroll
    for (int ct = 0; ct < 2; ++ct)
#pragma unroll
      for (int e = 0; e < 8; ++e)
        bf[ct][e] = ald(src, ks * 32 + kg * 8 + e, (c0 + ct * 16) * 2);
#pragma unroll
    for (int rt = 0; rt < 4; ++rt) {
      const unsigned int byte = (unsigned int)(mrow[rt] >> (ks * 32 + kg * 8)) & 0xffu;
      h8 af;
#pragma unroll
      for (int e = 0; e < 8; ++e) af[e] = (_Float16)((byte >> e) & 1u);
#pragma unroll
      for (int ct = 0; ct < 2; ++ct)
        acc[rt][ct] = __builtin_amdgcn_mfma_f32_16x16x32_f16(af, bf[ct], acc[rt][ct], 0, 0, 0);
    }
  }
#pragma unroll
  for (int rt = 0; rt < 4; ++rt)
#pragma unroll
    for (int ct = 0; ct < 2; ++ct)
#pragma unroll
      for (int q = 0; q < 4; ++q)
        ast(dst, rt * 16 + kg * 4 + q, (c0 + ct * 16) * 2, (_Float16)acc[rt][ct][q]);
}

// 32-wide aggregation, both graphs: waves 0-1 -> g0, waves 2-3 -> g1.
// src = XC (logical cols 32..63 of Q), dst = XL (logical cols 0..31) — disjoint.
__device__ __forceinline__ void agg32_2g(
    const u64* mc0, const u64* mc1, char* q0buf, char* q1buf, int tid)
{
  const int lane = tid & 63, wv = tid >> 6, lc = lane & 15, kg = lane >> 4;
  const int g = wv >> 1;
  const u64* mc = g ? mc1 : mc0;
  char* buf = g ? q1buf : q0buf;
  const int c0 = (wv & 1) * 16 + lc;
  u64 mrow[4];
#pragma unroll
  for (int rt = 0; rt < 4; ++rt) mrow[rt] = mc[rt * 16 + lc];
  f4 acc[4];
#pragma unroll
  for (int rt = 0; rt < 4; ++rt) acc[rt] = (f4){0.f,0.f,0.f,0.f};
#pragma unroll
  for (int ks = 0; ks < 2; ++ks) {
    h8 bf;
#pragma unroll
    for (int e = 0; e < 8; ++e) bf[e] = ald(buf, ks * 32 + kg * 8 + e, 64 + c0 * 2);
#pragma unroll
    for (int rt = 0; rt < 4; ++rt) {
      const unsigned int byte = (unsigned int)(mrow[rt] >> (ks * 32 + kg * 8)) & 0xffu;
      h8 af;
#pragma unroll
      for (int e = 0; e < 8; ++e) af[e] = (_Float16)((byte >> e) & 1u);
      acc[rt] = __builtin_amdgcn_mfma_f32_16x16x32_f16(af, bf, acc[rt], 0, 0, 0);
    }
  }
#pragma unroll
  for (int rt = 0; rt < 4; ++rt)
#pragma unroll
    for (int q = 0; q < 4; ++q)
      ast(buf, rt * 16 + kg * 4 + q, c0 * 2, (_Float16)acc[rt][q]);
}

// in-place LN over 128 f16 features, 4 threads/node, fp32 math (wave-local rows)
__device__ __forceinline__ void layer_norm(
    char* buf, const float* __restrict__ g, const float* __restrict__ b, int tid)
{
  const int n = tid >> 2, q = tid & 3;
  float vals[32];
#pragma unroll
  for (int u = 0; u < 4; ++u) {
    const h8 v = ald8(buf, n, q * 64 + u * 16);
#pragma unroll
    for (int e = 0; e < 8; ++e) vals[u * 8 + e] = (float)v[e];
  }
  float s = 0.f;
#pragma unroll
  for (int u = 0; u < 32; ++u) s += vals[u];
  s += __shfl_xor(s, 1, 64);
  s += __shfl_xor(s, 2, 64);
  const float mean = s * 0.0078125f;
  float vv = 0.f;
#pragma unroll
  for (int u = 0; u < 32; ++u) { const float d = vals[u] - mean; vv = fmaf(d, d, vv); }
  vv += __shfl_xor(vv, 1, 64);
  vv += __shfl_xor(vv, 2, 64);
  const float rstd = 1.0f / sqrtf(vv * 0.0078125f + 1e-5f);
#pragma unroll
  for (int u = 0; u < 4; ++u) {
    h8 o;
#pragma unroll
    for (int e = 0; e < 8; ++e) {
      const int col = q * 32 + u * 8 + e;
      o[e] = (_Float16)((vals[u * 8 + e] - mean) * rstd * g[col] + b[col]);
    }
    ast8(buf, n, q * 64 + u * 16, o);
  }
}

struct SM {
  alignas(16) char act[4][16384];   // P0,Q0,P1,Q1 (Q holds XL cols 0..31 / XC 32..63 early)
  alignas(16) char WB[3][4096];     // triple-buffered weight chunks
  float pos[2][NN * 2];
  u64 mcol[2][NN];
};                                  // 79872 B -> 2 blocks/CU

__global__ __launch_bounds__(256, 2)
void gin_critic_kernel(
    const float* __restrict__ data,
    const float* __restrict__ b_l1, const float* __restrict__ b_l2,
    const float* __restrict__ b11, const float* __restrict__ b12,
    const float* __restrict__ b21, const float* __restrict__ b22,
    const float* __restrict__ bqkv, const float* __restrict__ bo,
    const float* __restrict__ ln1_g, const float* __restrict__ ln1_b,
    const float* __restrict__ bf1, const float* __restrict__ bf2,
    const float* __restrict__ ln2_g, const float* __restrict__ ln2_b,
    const float* __restrict__ Wfc, const float* __restrict__ bfc,
    const _Float16* __restrict__ ws,
    float* __restrict__ out)
{
  __shared__ SM sm;
  const int tid = threadIdx.x;
  const int b = blockIdx.x;
  const long base = (long)b * 2 * NN * 27;

  char* P0 = sm.act[0];
  char* Q0 = sm.act[1];
  char* P1 = sm.act[2];
  char* Q1 = sm.act[3];
  char* wbase = sm.WB[0];
  int wbi = 0;

  const _Float16* Wl1p = ws + 0;
  const _Float16* Wl2p = ws + 4096;
  const _Float16* W11p = ws + 8192;
  const _Float16* W12p = ws + 12288;
  const _Float16* W21p = ws + 28672;
  const _Float16* W22p = ws + 45056;

  // prologue: get lidar1's two chunks flying first
  stage64(Wl1p, 32, 0, 0, wbase + 0 * 4096, tid);
  stage64(Wl1p, 32, 0, 1, wbase + 1 * 4096, tid);

  // ---- stage inputs for both graphs: XC cols 32..38=orig7, XL cols 0..19=lidar ----
  for (int idx = tid; idx < 2 * NN * 27; idx += 256) {
    const int gi = idx / (NN * 27);
    const int r = idx - gi * (NN * 27);
    const int n = r / 27;
    const int f = r - n * 27;
    const float v = data[base + idx];
    if (f < 2) sm.pos[gi][n * 2 + f] = v;
    char* Qg = gi ? Q1 : Q0;
    if (f < 7) ast(Qg, n, 64 + f * 2, (_Float16)v);
    else       ast(Qg, n, (f - 7) * 2, (_Float16)v);
  }
  if (tid < 128) {
    const int gi = tid >> 6, n = tid & 63;
    char* Qg = gi ? Q1 : Q0;
#pragma unroll
    for (int c = 20; c < 32; ++c) ast(Qg, n, c * 2, (_Float16)0.f);
#pragma unroll
    for (int c = 27; c < 32; ++c) ast(Qg, n, 64 + c * 2, (_Float16)0.f);
  }
  __syncthreads();   // inputs visible + prologue chunks drained (vmcnt 0)

  // ---- adjacency masks (exact double cone + guard-band atan2 fallback) ----
  {
    const int lane = tid & 63;
    const int wv = tid >> 6;
    const int g = wv >> 1;
    const float x0 = sm.pos[g][lane * 2 + 0];
    const float x1 = sm.pos[g][lane * 2 + 1];
    const float FOVF = (float)(0.35 * 3.14159265358979323846);
    const double TT = tan(0.35 * 3.14159265358979323846);
    const double T2 = TT * TT;
    for (int jj = 0; jj < 32; ++jj) {
      const int j = (wv & 1) * 32 + jj;
      const float x0j = __shfl(x0, j, 64);
      const float x1j = __shfl(x1, j, 64);
      const float dxf = x0 - x0j;
      const float dyf = x1 - x1j;
      const float dist = sqrtf(dxf * dxf + dyf * dyf);
      bool pred;
      if (lane == j || dist > 10.0f) {
        pred = false;
      } else if (dxf <= 0.0f) {
        pred = (dxf == 0.0f && dyf == 0.0f);
      } else {
        const double qa = (double)dyf * (double)dyf;
        const double qb = (double)dxf * (double)dxf * T2;
        if (qa <= qb * 0.99999) pred = true;
        else if (qa >= qb * 1.00001) pred = false;
        else pred = (fabsf((float)atan2((double)dyf, (double)dxf)) <= FOVF);
      }
      const u64 bal = __ballot(pred);
      if (lane == 0) sm.mcol[g][j] = bal | (1ull << j);
    }
  }

  // lidar MLP: lidar1 (src XL in Q, dst P), lidar2 (src P, dst XC cols 7..26 in Q)
  mm2_s64<32, true, false, true>(Wl1p, b_l1, Q0, Q1, 0, P0, P1, nullptr, nullptr,
      wbase, wbi, tid, [&](int s, int bi) { stage32(Wl2p, s, wbase + bi * 4096, tid); });
  mm2_s32(Wl2p, b_l2, P0, P1, Q0, Q1,
      wbase, wbi, tid, [&](int s, int bi) { stage64(W11p, 32, 0, s, wbase + bi * 4096, tid); });
  __syncthreads();   // XC complete (cross-wave for agg32); drains W11 prefetch (ok)

  // GIN layer 1
  agg32_2g(sm.mcol[0], sm.mcol[1], Q0, Q1, tid);   // XL = (M+I)^T x (in-Q, disjoint cols)
  __syncthreads();
  mm2_s64<32, true, false, true>(W11p, b11, Q0, Q1, 0, P0, P1, nullptr, nullptr,
      wbase, wbi, tid, [&](int s, int bi) { stage64(W12p, 128, 0, s, wbase + bi * 4096, tid); });
  mm2_s64<128, true, false, true>(W12p, b12, P0, P1, 0, Q0, Q1, nullptr, nullptr,
      wbase, wbi, tid, [&](int s, int bi) { stage64(W21p, 128, 0, s, wbase + bi * 4096, tid); });
  __syncthreads();   // h complete (cross-wave for agg128)

  // GIN layer 2
  agg128(sm.mcol[0], Q0, P0, tid);
  agg128(sm.mcol[1], Q1, P1, tid);
  __syncthreads();
  mm2_s64<128, true, false, true>(W21p, b21, P0, P1, 0, Q0, Q1, nullptr, nullptr,
      wbase, wbi, tid, [&](int s, int bi) { stage64(W22p, 128, 0, s, wbase + bi * 4096, tid); });
  mm2_s64<128, true, false, true>(W22p, b22, Q0, Q1, 0, P0, P1, nullptr, nullptr,
      wbase, wbi, tid, [&](int s, int bi) { stage64(ws + 61440, 128, 0, s, wbase + bi * 4096, tid); });

  // transformer layer 0
  {
    const _Float16* Wvp  = ws + 61440;
    const _Float16* Wop  = ws + 94208;
    const _Float16* Wf1p = ws + 126976;
    const _Float16* Wf2p = ws + 159744;
    mm2_s64<128, false, false, true>(Wvp, bqkv + 256, P0, P1, 0, Q0, Q1, nullptr, nullptr,
        wbase, wbi, tid, [&](int s, int bi) { stage64(Wop, 128, 0, s, wbase + bi * 4096, tid); });
    mm2_s64<128, false, true, true>(Wop, bo, Q0, Q1, 0, P0, P1, P0, P1,
        wbase, wbi, tid, [&](int s, int bi) { stage64(Wf1p, 128, 0, s, wbase + bi * 4096, tid); });
    layer_norm(P0, ln1_g, ln1_b, tid);
    layer_norm(P1, ln1_g, ln1_b, tid);
    mm2_s64<128, true, false, true>(Wf1p, bf1, P0, P1, 0, Q0, Q1, nullptr, nullptr,
        wbase, wbi, tid, [&](int s, int bi) { stage64(Wf2p, 128, 0, s, wbase + bi * 4096, tid); });
    mm2_s64<128, false, true, true>(Wf2p, bf2, Q0, Q1, 0, P0, P1, P0, P1,
        wbase, wbi, tid, [&](int s, int bi) { stage64(ws + 61440 + 16384, 128, 0, s, wbase + bi * 4096, tid); });
    layer_norm(P0, ln2_g, ln2_b, tid);
    layer_norm(P1, ln2_g, ln2_b, tid);
  }
  // transformer layer 1 (last stage CONT=false)
  {
    const _Float16* Wvp  = ws + 61440 + 16384;
    const _Float16* Wop  = ws + 94208 + 16384;
    const _Float16* Wf1p = ws + 126976 + 16384;
    const _Float16* Wf2p = ws + 159744 + 16384;
    mm2_s64<128, false, false, true>(Wvp, bqkv + 384 + 256, P0, P1, 0, Q0, Q1, nullptr, nullptr,
        wbase, wbi, tid, [&](int s, int bi) { stage64(Wop, 128, 0, s, wbase + bi * 4096, tid); });
    mm2_s64<128, false, true, true>(Wop, bo + 128, Q0, Q1, 0, P0, P1, P0, P1,
        wbase, wbi, tid, [&](int s, int bi) { stage64(Wf1p, 128, 0, s, wbase + bi * 4096, tid); });
    layer_norm(P0, ln1_g + 128, ln1_b + 128, tid);
    layer_norm(P1, ln1_g + 128, ln1_b + 128, tid);
    mm2_s64<128, true, false, true>(Wf1p, bf1 + 128, P0, P1, 0, Q0, Q1, nullptr, nullptr,
        wbase, wbi, tid, [&](int s, int bi) { stage64(Wf2p, 128, 0, s, wbase + bi * 4096, tid); });
    mm2_s64<128, false, true, false>(Wf2p, bf2 + 128, Q0, Q1, 0, P0, P1, P0, P1,
        wbase, wbi, tid, [&](int, int) {});
    layer_norm(P0, ln2_g + 128, ln2_b + 128, tid);
    layer_norm(P1, ln2_g + 128, ln2_b + 128, tid);
  }

  // final head (wave-local rows)
#pragma unroll
  for (int g = 0; g < 2; ++g) {
    const char* Pg = g ? P1 : P0;
    const int n = tid >> 2, q = tid & 3;
    float s = 0.f;
#pragma unroll
    for (int u = 0; u < 4; ++u) {
      const h8 v = ald8(Pg, n, q * 64 + u * 16);
      const float4 w0 = *(const float4*)(Wfc + q * 32 + u * 8);
      const float4 w1 = *(const float4*)(Wfc + q * 32 + u * 8 + 4);
      s = fmaf((float)v[0], w0.x, s); s = fmaf((float)v[1], w0.y, s);
      s = fmaf((float)v[2], w0.z, s); s = fmaf((float)v[3], w0.w, s);
      s = fmaf((float)v[4], w1.x, s); s = fmaf((float)v[5], w1.y, s);
      s = fmaf((float)v[6], w1.z, s); s = fmaf((float)v[7], w1.w, s);
    }
    s += __shfl_xor(s, 1, 64);
    s += __shfl_xor(s, 2, 64);
    if (q == 0) out[((long)b * 2 + g) * NN + n] = s + bfc[0];
  }
}

extern "C" void kernel_launch(void* const* d_in, const int* in_sizes, int n_in,
                              void* d_out, int out_size, void* d_ws, size_t ws_size,
                              hipStream_t stream) {
  const float* data  = (const float*)d_in[0];
  const float* W_l1  = (const float*)d_in[1];
  const float* b_l1  = (const float*)d_in[2];
  const float* W_l2  = (const float*)d_in[3];
  const float* b_l2  = (const float*)d_in[4];
  const float* W11   = (const float*)d_in[5];
  const float* b11   = (const float*)d_in[6];
  const float* W12   = (const float*)d_in[7];
  const float* b12   = (const float*)d_in[8];
  const float* W21   = (const float*)d_in[9];
  const float* b21   = (const float*)d_in[10];
  const float* W22   = (const float*)d_in[11];
  const float* b22   = (const float*)d_in[12];
  const float* Wqkv  = (const float*)d_in[13];
  const float* bqkv  = (const float*)d_in[14];
  const float* Wo    = (const float*)d_in[15];
  const float* bo    = (const float*)d_in[16];
  const float* ln1_g = (const float*)d_in[17];
  const float* ln1_b = (const float*)d_in[18];
  const float* Wf1   = (const float*)d_in[19];
  const float* bf1   = (const float*)d_in[20];
  const float* Wf2   = (const float*)d_in[21];
  const float* bf2   = (const float*)d_in[22];
  const float* ln2_g = (const float*)d_in[23];
  const float* ln2_b = (const float*)d_in[24];
  const float* Wfc   = (const float*)d_in[25];
  const float* bfc   = (const float*)d_in[26];

  _Float16* ws = (_Float16*)d_ws;

  prep_kernel<<<dim3(752), dim3(256), 0, stream>>>(
      W_l1, W_l2, W11, W12, W21, W22, Wqkv, Wo, Wf1, Wf2, ws);

  gin_critic_kernel<<<dim3(NB / 2), dim3(256), 0, stream>>>(
      data, b_l1, b_l2, b11, b12, b21, b22, bqkv, bo,
      ln1_g, ln1_b, bf1, bf2, ln2_g, ln2_b, Wfc, bfc,
      ws, (float*)d_out);
}